// Round 1
// baseline (241.752 us; speedup 1.0000x reference)
//
#include <hip/hip_runtime.h>
#include <hip/hip_bf16.h>

#define NN 512
#define DD 64
#define TOPK 20
#define BB 128

// ---------------- K1: cos similarity + top-k + emb-attn partial scores ----------
__global__ __launch_bounds__(256) void k1_topk(const float* __restrict__ emb,
                                               const float* __restrict__ attn_w,
                                               int* __restrict__ topk,
                                               float* __restrict__ es_src,
                                               float* __restrict__ es_dst) {
    __shared__ double cosv[NN];
    __shared__ double redv[256];
    __shared__ int    redi[256];
    __shared__ float  wi[DD];
    const int i = blockIdx.x;
    const int t = threadIdx.x;
    if (t < DD) wi[t] = emb[i * DD + t];
    __syncthreads();

    double di = 0.0;
    #pragma unroll
    for (int f = 0; f < DD; ++f) di += (double)wi[f] * (double)wi[f];
    const double nrm_i = sqrt(di);

    for (int j = t; j < NN; j += 256) {
        double dot = 0.0, dj = 0.0;
        #pragma unroll
        for (int f = 0; f < DD; ++f) {
            double wjf = (double)emb[j * DD + f];
            dot += (double)wi[f] * wjf;
            dj  += wjf * wjf;
        }
        cosv[j] = dot / (nrm_i * sqrt(dj));
    }
    __syncthreads();

    for (int k = 0; k < TOPK; ++k) {
        double v0 = cosv[t], v1 = cosv[t + 256];
        double bv; int bi;
        if (v1 > v0) { bv = v1; bi = t + 256; } else { bv = v0; bi = t; }
        redv[t] = bv; redi[t] = bi;
        __syncthreads();
        for (int s = 128; s > 0; s >>= 1) {
            if (t < s) {
                double ov = redv[t + s]; int oi = redi[t + s];
                if (ov > redv[t] || (ov == redv[t] && oi < redi[t])) {
                    redv[t] = ov; redi[t] = oi;
                }
            }
            __syncthreads();
        }
        if (t == 0) {
            topk[i * TOPK + k] = redi[0];
            cosv[redi[0]] = -1e300;
        }
        __syncthreads();
    }

    // es_src[i] = emb[i,:] . attn_w[64:128]; es_dst[i] = emb[i,:] . attn_w[192:256]
    if (t < 64) {
        float v1 = wi[t] * attn_w[64 + t];
        float v2 = wi[t] * attn_w[192 + t];
        #pragma unroll
        for (int off = 32; off > 0; off >>= 1) {
            v1 += __shfl_down(v1, off);
            v2 += __shfl_down(v2, off);
        }
        if (t == 0) { es_src[i] = v1; es_dst[i] = v2; }
    }
}

// ---------------- K2: z = data @ fc_w^T + fc_b  (rows = B*N, inner = Ft=64) ------
__global__ __launch_bounds__(256) void k2_gemm(const float* __restrict__ data,
                                               const float* __restrict__ fc_w,
                                               const float* __restrict__ fc_b,
                                               float* __restrict__ z) {
    __shared__ float As[64][65];
    __shared__ float Ws[64][65];
    const int t = threadIdx.x;
    const long r0 = (long)blockIdx.x * 64;

    for (int idx = t; idx < 4096; idx += 256) {
        As[idx >> 6][idx & 63] = data[r0 * 64 + idx];
        Ws[idx >> 6][idx & 63] = fc_w[idx];
    }
    __syncthreads();

    const int tr = t >> 4, tc = t & 15;
    float acc[4][4] = {};
    for (int k = 0; k < 64; ++k) {
        float a[4], b[4];
        #pragma unroll
        for (int i = 0; i < 4; ++i) a[i] = As[tr * 4 + i][k];
        #pragma unroll
        for (int j = 0; j < 4; ++j) b[j] = Ws[tc * 4 + j][k];
        #pragma unroll
        for (int i = 0; i < 4; ++i)
            #pragma unroll
            for (int j = 0; j < 4; ++j) acc[i][j] += a[i] * b[j];
    }
    float bias[4];
    #pragma unroll
    for (int j = 0; j < 4; ++j) bias[j] = fc_b[tc * 4 + j];
    #pragma unroll
    for (int i = 0; i < 4; ++i) {
        float4 v;
        v.x = acc[i][0] + bias[0];
        v.y = acc[i][1] + bias[1];
        v.z = acc[i][2] + bias[2];
        v.w = acc[i][3] + bias[3];
        *(float4*)&z[(r0 + tr * 4 + i) * 64 + tc * 4] = v;
    }
}

// ---------------- K2b: s_src/s_dst per (b,n) row --------------------------------
__global__ __launch_bounds__(256) void k2b_scores(const float* __restrict__ z,
                                                  const float* __restrict__ attn_w,
                                                  const float* __restrict__ es_src,
                                                  const float* __restrict__ es_dst,
                                                  float* __restrict__ s_src,
                                                  float* __restrict__ s_dst) {
    const int wid = threadIdx.x >> 6;
    const int lane = threadIdx.x & 63;
    const long row = (long)blockIdx.x * 4 + wid;
    const float zv = z[row * 64 + lane];
    float v1 = zv * attn_w[lane];
    float v2 = zv * attn_w[128 + lane];
    #pragma unroll
    for (int off = 32; off > 0; off >>= 1) {
        v1 += __shfl_down(v1, off);
        v2 += __shfl_down(v2, off);
    }
    if (lane == 0) {
        const int n = (int)(row & (NN - 1));
        s_src[row] = v1 + es_src[n];
        s_dst[row] = v2 + es_dst[n];
    }
}

// ---------------- K3: edge softmax + gather + rst + BN partials ------------------
__global__ __launch_bounds__(256) void k3_attn(const float* __restrict__ z,
                                               const float* __restrict__ s_src,
                                               const float* __restrict__ s_dst,
                                               const int* __restrict__ topk,
                                               const float* __restrict__ emb,
                                               const float* __restrict__ attn_b_p,
                                               float* __restrict__ rst,
                                               double* __restrict__ bsum,
                                               double* __restrict__ bsum2) {
    const int b   = blockIdx.x >> 3;   // 128 batches
    const int nc  = blockIdx.x & 7;    // 8 chunks of 64 n
    const int wid = threadIdx.x >> 6, lane = threadIdx.x & 63;
    const float attn_b = *attn_b_p;
    const float* zb  = z + (long)b * NN * DD;
    const float* ssb = s_src + b * NN;

    double sum1 = 0.0, sum2 = 0.0;
    for (int q = 0; q < 16; ++q) {
        const int n = nc * 64 + wid * 16 + q;
        const float sd = s_dst[b * NN + n];
        float ev[TOPK]; int si[TOPK];
        float m = -1e30f;
        #pragma unroll
        for (int tt = 0; tt < TOPK; ++tt) {
            const int s = topk[n + tt * NN];   // flat src index per scrambled edge list
            si[tt] = s;
            float e = ssb[s] + sd + attn_b;
            e = (e >= 0.f) ? e : 0.2f * e;     // leaky_relu
            ev[tt] = e;
            m = fmaxf(m, e);
        }
        float denom = 0.f;
        #pragma unroll
        for (int tt = 0; tt < TOPK; ++tt) { ev[tt] = __expf(ev[tt] - m); denom += ev[tt]; }
        const float inv = 1.0f / denom;
        float acc = 0.f;
        #pragma unroll
        for (int tt = 0; tt < TOPK; ++tt) {
            acc += (ev[tt] * inv) * zb[(long)si[tt] * 64 + lane];
        }
        const float r = acc * emb[n * 64 + lane];
        rst[((long)b * NN + n) * 64 + lane] = r;
        sum1 += (double)r;
        sum2 += (double)r * (double)r;
    }

    __shared__ double ls1[4][64], ls2[4][64];
    ls1[wid][lane] = sum1;
    ls2[wid][lane] = sum2;
    __syncthreads();
    if (wid == 0) {
        double a = ls1[0][lane] + ls1[1][lane] + ls1[2][lane] + ls1[3][lane];
        double c = ls2[0][lane] + ls2[1][lane] + ls2[2][lane] + ls2[3][lane];
        bsum [blockIdx.x * 64 + lane] = a;
        bsum2[blockIdx.x * 64 + lane] = c;
    }
}

// ---------------- K4: BN finalize -> scale/bias ---------------------------------
__global__ __launch_bounds__(64) void k4_bn(const double* __restrict__ bsum,
                                            const double* __restrict__ bsum2,
                                            const float* __restrict__ gamma,
                                            const float* __restrict__ beta,
                                            float* __restrict__ scaleArr,
                                            float* __restrict__ biasArr) {
    const int d = threadIdx.x;
    double s = 0.0, s2 = 0.0;
    for (int blk = 0; blk < 1024; ++blk) {
        s  += bsum [blk * 64 + d];
        s2 += bsum2[blk * 64 + d];
    }
    const double M = (double)BB * (double)NN;
    const double mu  = s / M;
    const double var = s2 / M - mu * mu;
    const float scale = (float)((double)gamma[d] / sqrt(var + 1e-5));
    scaleArr[d] = scale;
    biasArr[d]  = beta[d] - (float)mu * scale;
}

// ---------------- K5: BN apply + ReLU + out_w dot -------------------------------
__global__ __launch_bounds__(256) void k5_out(const float* __restrict__ rst,
                                              const float* __restrict__ scaleArr,
                                              const float* __restrict__ biasArr,
                                              const float* __restrict__ out_w,
                                              const float* __restrict__ out_b_p,
                                              float* __restrict__ out) {
    const int wid = threadIdx.x >> 6, lane = threadIdx.x & 63;
    const long row = (long)blockIdx.x * 4 + wid;
    const float r = rst[row * 64 + lane];
    float v = fmaxf(r * scaleArr[lane] + biasArr[lane], 0.f) * out_w[lane];
    #pragma unroll
    for (int off = 32; off > 0; off >>= 1) v += __shfl_down(v, off);
    if (lane == 0) out[row] = v + *out_b_p;
}

extern "C" void kernel_launch(void* const* d_in, const int* in_sizes, int n_in,
                              void* d_out, int out_size, void* d_ws, size_t ws_size,
                              hipStream_t stream) {
    const float* data   = (const float*)d_in[0];  // (B,N,Ft)
    const float* emb    = (const float*)d_in[1];  // (N,D)
    const float* fc_w   = (const float*)d_in[2];  // (D,Ft)
    const float* fc_b   = (const float*)d_in[3];  // (D,)
    const float* attn_w = (const float*)d_in[4];  // (4D,)
    const float* attn_b = (const float*)d_in[5];  // ()
    const float* gamma  = (const float*)d_in[6];  // (D,)
    const float* beta   = (const float*)d_in[7];  // (D,)
    const float* out_w  = (const float*)d_in[8];  // (D,)
    const float* out_b  = (const float*)d_in[9];  // ()
    float* out = (float*)d_out;

    char* ws = (char*)d_ws;
    const long ROWS = (long)BB * NN;               // 65536
    float*  z      = (float*) (ws + 0);            // 16 MB
    float*  rst    = (float*) (ws + 16777216);     // 16 MB
    float*  s_src  = (float*) (ws + 33554432);     // 256 KB
    float*  s_dst  = (float*) (ws + 33816576);     // 256 KB
    int*    topk   = (int*)   (ws + 34078720);     // 40 KB
    float*  es_src = (float*) (ws + 34119680);     // 2 KB
    float*  es_dst = (float*) (ws + 34121728);     // 2 KB
    double* bsum   = (double*)(ws + 34123776);     // 512 KB (8B aligned)
    double* bsum2  = (double*)(ws + 34648064);     // 512 KB
    float*  scaleA = (float*) (ws + 35172352);     // 256 B
    float*  biasA  = (float*) (ws + 35172608);     // 256 B

    k1_topk<<<NN, 256, 0, stream>>>(emb, attn_w, topk, es_src, es_dst);
    k2_gemm<<<(int)(ROWS / 64), 256, 0, stream>>>(data, fc_w, fc_b, z);
    k2b_scores<<<(int)(ROWS / 4), 256, 0, stream>>>(z, attn_w, es_src, es_dst, s_src, s_dst);
    k3_attn<<<BB * 8, 256, 0, stream>>>(z, s_src, s_dst, topk, emb, attn_b, rst, bsum, bsum2);
    k4_bn<<<1, 64, 0, stream>>>(bsum, bsum2, gamma, beta, scaleA, biasA);
    k5_out<<<(int)(ROWS / 4), 256, 0, stream>>>(rst, scaleA, biasA, out_w, out_b, out);
}

// Round 2
// 165.839 us; speedup vs baseline: 1.4578x; 1.4578x over previous
//
#include <hip/hip_runtime.h>
#include <hip/hip_bf16.h>

#define NN 512
#define DD 64
#define TOPK 20
#define BB 128

// ---------------- K1: cos similarity + top-k + emb-attn partial scores ----------
// One wave per node i. Each lane owns 8 candidate rows j = lane*8+r in registers.
// f64 math with identical accumulation order / tie-break as the verified round-1
// kernel (max value, smallest index on ties) -> bit-identical topk indices.
__global__ __launch_bounds__(64) void k1_topk(const float* __restrict__ emb,
                                              const float* __restrict__ attn_w,
                                              int* __restrict__ topk,
                                              float* __restrict__ es_src,
                                              float* __restrict__ es_dst) {
    const int i = blockIdx.x;
    const int lane = threadIdx.x;
    const float4* e4 = (const float4*)emb;

    double dot[8] = {0,0,0,0,0,0,0,0};
    double dj [8] = {0,0,0,0,0,0,0,0};
    double di = 0.0;

    for (int c = 0; c < 16; ++c) {
        float4 wi4 = e4[i * 16 + c];
        double wx = wi4.x, wy = wi4.y, wz = wi4.z, ww = wi4.w;
        di += wx * wx; di += wy * wy; di += wz * wz; di += ww * ww;
        #pragma unroll
        for (int r = 0; r < 8; ++r) {
            float4 v = e4[(lane * 8 + r) * 16 + c];
            double vx = v.x, vy = v.y, vz = v.z, vw = v.w;
            dot[r] += wx * vx; dot[r] += wy * vy; dot[r] += wz * vz; dot[r] += ww * vw;
            dj [r] += vx * vx; dj [r] += vy * vy; dj [r] += vz * vz; dj [r] += vw * vw;
        }
    }
    const double nrm_i = sqrt(di);
    double v[8];
    #pragma unroll
    for (int r = 0; r < 8; ++r) v[r] = dot[r] / (nrm_i * sqrt(dj[r]));

    for (int k = 0; k < TOPK; ++k) {
        double bv = v[0]; int br = 0;
        #pragma unroll
        for (int r = 1; r < 8; ++r) if (v[r] > bv) { bv = v[r]; br = r; }
        int bi = lane * 8 + br;
        #pragma unroll
        for (int off = 32; off > 0; off >>= 1) {
            double ov = __shfl_xor(bv, off);
            int    oi = __shfl_xor(bi, off);
            if (ov > bv || (ov == bv && oi < bi)) { bv = ov; bi = oi; }
        }
        if (lane == 0) topk[i * TOPK + k] = bi;
        if ((bi >> 3) == lane) v[bi & 7] = -1e300;
    }

    // es_src[i] = emb[i,:].attn_w[64:128]; es_dst[i] = emb[i,:].attn_w[192:256]
    float wf = emb[i * 64 + lane];
    float v1 = wf * attn_w[64 + lane];
    float v2 = wf * attn_w[192 + lane];
    #pragma unroll
    for (int off = 32; off > 0; off >>= 1) {
        v1 += __shfl_xor(v1, off);
        v2 += __shfl_xor(v2, off);
    }
    if (lane == 0) { es_src[i] = v1; es_dst[i] = v2; }
}

// ---------------- K2: z = data @ fc_w^T + fc_b, fused s_src/s_dst ---------------
__global__ __launch_bounds__(256) void k2_gemm(const float* __restrict__ data,
                                               const float* __restrict__ fc_w,
                                               const float* __restrict__ fc_b,
                                               const float* __restrict__ attn_w,
                                               const float* __restrict__ es_src,
                                               const float* __restrict__ es_dst,
                                               float* __restrict__ z,
                                               float* __restrict__ s_src,
                                               float* __restrict__ s_dst) {
    __shared__ float As[64][65];
    __shared__ float Ws[64][65];
    __shared__ float redA[64][17];
    __shared__ float redB[64][17];
    const int t = threadIdx.x;
    const long r0 = (long)blockIdx.x * 64;

    for (int idx = t; idx < 4096; idx += 256) {
        As[idx >> 6][idx & 63] = data[r0 * 64 + idx];
        Ws[idx >> 6][idx & 63] = fc_w[idx];
    }
    __syncthreads();

    const int tr = t >> 4, tc = t & 15;
    float acc[4][4] = {};
    for (int k = 0; k < 64; ++k) {
        float a[4], b[4];
        #pragma unroll
        for (int i = 0; i < 4; ++i) a[i] = As[tr * 4 + i][k];
        #pragma unroll
        for (int j = 0; j < 4; ++j) b[j] = Ws[tc * 4 + j][k];
        #pragma unroll
        for (int i = 0; i < 4; ++i)
            #pragma unroll
            for (int j = 0; j < 4; ++j) acc[i][j] += a[i] * b[j];
    }
    float bias[4], aw0[4], aw2[4];
    #pragma unroll
    for (int j = 0; j < 4; ++j) {
        bias[j] = fc_b[tc * 4 + j];
        aw0[j]  = attn_w[tc * 4 + j];
        aw2[j]  = attn_w[128 + tc * 4 + j];
    }
    #pragma unroll
    for (int i = 0; i < 4; ++i) {
        float zb[4];
        #pragma unroll
        for (int j = 0; j < 4; ++j) zb[j] = acc[i][j] + bias[j];
        float4 vv; vv.x = zb[0]; vv.y = zb[1]; vv.z = zb[2]; vv.w = zb[3];
        *(float4*)&z[(r0 + tr * 4 + i) * 64 + tc * 4] = vv;
        float pA = zb[0] * aw0[0] + zb[1] * aw0[1] + zb[2] * aw0[2] + zb[3] * aw0[3];
        float pB = zb[0] * aw2[0] + zb[1] * aw2[1] + zb[2] * aw2[2] + zb[3] * aw2[3];
        redA[tr * 4 + i][tc] = pA;
        redB[tr * 4 + i][tc] = pB;
    }
    __syncthreads();
    if (t < 64) {
        float sA = 0.f, sB = 0.f;
        #pragma unroll
        for (int k = 0; k < 16; ++k) { sA += redA[t][k]; sB += redB[t][k]; }
        const int n = (int)((r0 + t) & (NN - 1));
        s_src[r0 + t] = sA + es_src[n];
        s_dst[r0 + t] = sB + es_dst[n];
    }
}

// ---------------- K3: LDS-staged gather + one-shot softmax + BN partials --------
// grid: 512 blocks = (batch b, feature-quarter dq). Stages z_b[:, dq*16:+16]
// (32 KB) in LDS; z is read exactly once from global across the whole kernel.
// Per 256-row chunk: phase 1 computes each row's 20-edge softmax ONCE
// (1 thread/row) into LDS; phase 2 does the gather-FMA from LDS.
__global__ __launch_bounds__(256) void k3_attn(const float* __restrict__ z,
                                               const float* __restrict__ s_src,
                                               const float* __restrict__ s_dst,
                                               const int* __restrict__ topk,
                                               const float* __restrict__ emb,
                                               const float* __restrict__ attn_b_p,
                                               float* __restrict__ rst,
                                               double* __restrict__ bsum,
                                               double* __restrict__ bsum2) {
    __shared__ float  zs[512 * 16];          // 32 KB
    __shared__ double alf_pool[2560];        // 20 KB: alpha[256][20] / BN-reduce alias
    __shared__ unsigned short sIdx[256 * 20];// 10 KB
    float* alf = (float*)alf_pool;

    const int b   = blockIdx.x >> 2;
    const int dq  = blockIdx.x & 3;
    const int doff = dq * 16;
    const int t   = threadIdx.x;
    const float attn_b = *attn_b_p;
    const long b512 = (long)b * NN;

    // stage z slice: zs[n*16+c] = z[(b*512+n)*64 + doff + c]
    float4* zs4 = (float4*)zs;
    for (int m = t; m < 2048; m += 256) {
        const int n = m >> 2, c4 = m & 3;
        zs4[m] = *(const float4*)(z + (b512 + n) * 64 + doff + c4 * 4);
    }
    __syncthreads();

    const int g = t >> 4, c = t & 15;
    double sum1 = 0.0, sum2 = 0.0;

    for (int chunk = 0; chunk < 2; ++chunk) {
        // ---- phase 1: one thread per row computes the 20-edge softmax ----
        {
            const int n = chunk * 256 + t;
            const float sd = s_dst[b512 + n];
            float ev[TOPK];
            float m0 = -1e30f;
            #pragma unroll
            for (int tt = 0; tt < TOPK; ++tt) {
                const int s = topk[n + tt * NN];
                sIdx[t * TOPK + tt] = (unsigned short)s;
                float e = s_src[b512 + s] + sd + attn_b;
                e = (e >= 0.f) ? e : 0.2f * e;
                ev[tt] = e;
                m0 = fmaxf(m0, e);
            }
            float dsum = 0.f;
            #pragma unroll
            for (int tt = 0; tt < TOPK; ++tt) { ev[tt] = __expf(ev[tt] - m0); dsum += ev[tt]; }
            const float inv = 1.0f / dsum;
            #pragma unroll
            for (int tt = 0; tt < TOPK; ++tt) alf[t * TOPK + tt] = ev[tt] * inv;
        }
        __syncthreads();

        // ---- phase 2: gather-FMA from LDS, 16 lanes per row ----
        for (int it = 0; it < 16; ++it) {
            const int nl = g * 16 + it;
            const int n  = chunk * 256 + nl;
            float acc = 0.f;
            #pragma unroll
            for (int tt = 0; tt < TOPK; ++tt) {
                acc += alf[nl * TOPK + tt] * zs[(int)sIdx[nl * TOPK + tt] * 16 + c];
            }
            const float r = acc * emb[n * 64 + doff + c];
            rst[(b512 + n) * 64 + doff + c] = r;
            sum1 += (double)r;
            sum2 += (double)r * (double)r;
        }
        __syncthreads();   // before next chunk overwrites alf/sIdx
    }

    // ---- BN partials: alias reduce arrays onto alf_pool ----
    double* r1 = alf_pool;
    double* r2 = alf_pool + 256;
    r1[t] = sum1; r2[t] = sum2;
    __syncthreads();
    if (t < 16) {
        double a = 0.0, bb = 0.0;
        for (int g2 = 0; g2 < 16; ++g2) { a += r1[g2 * 16 + t]; bb += r2[g2 * 16 + t]; }
        bsum [blockIdx.x * 16 + t] = a;
        bsum2[blockIdx.x * 16 + t] = bb;
    }
}

// ---------------- K4: BN finalize -> scale/bias ---------------------------------
__global__ __launch_bounds__(64) void k4_bn(const double* __restrict__ bsum,
                                            const double* __restrict__ bsum2,
                                            const float* __restrict__ gamma,
                                            const float* __restrict__ beta,
                                            float* __restrict__ scaleArr,
                                            float* __restrict__ biasArr) {
    const int d = threadIdx.x;
    const int dq = d >> 4, c = d & 15;
    double s = 0.0, s2 = 0.0;
    for (int b = 0; b < BB; ++b) {
        const int blk = b * 4 + dq;
        s  += bsum [blk * 16 + c];
        s2 += bsum2[blk * 16 + c];
    }
    const double M = (double)BB * (double)NN;
    const double mu  = s / M;
    const double var = s2 / M - mu * mu;
    const float scale = (float)((double)gamma[d] / sqrt(var + 1e-5));
    scaleArr[d] = scale;
    biasArr[d]  = beta[d] - (float)mu * scale;
}

// ---------------- K5: BN apply + ReLU + out_w dot -------------------------------
__global__ __launch_bounds__(256) void k5_out(const float* __restrict__ rst,
                                              const float* __restrict__ scaleArr,
                                              const float* __restrict__ biasArr,
                                              const float* __restrict__ out_w,
                                              const float* __restrict__ out_b_p,
                                              float* __restrict__ out) {
    const int wid = threadIdx.x >> 6, lane = threadIdx.x & 63;
    const long row = (long)blockIdx.x * 4 + wid;
    const float r = rst[row * 64 + lane];
    float v = fmaxf(r * scaleArr[lane] + biasArr[lane], 0.f) * out_w[lane];
    #pragma unroll
    for (int off = 32; off > 0; off >>= 1) v += __shfl_down(v, off);
    if (lane == 0) out[row] = v + *out_b_p;
}

extern "C" void kernel_launch(void* const* d_in, const int* in_sizes, int n_in,
                              void* d_out, int out_size, void* d_ws, size_t ws_size,
                              hipStream_t stream) {
    const float* data   = (const float*)d_in[0];
    const float* emb    = (const float*)d_in[1];
    const float* fc_w   = (const float*)d_in[2];
    const float* fc_b   = (const float*)d_in[3];
    const float* attn_w = (const float*)d_in[4];
    const float* attn_b = (const float*)d_in[5];
    const float* gamma  = (const float*)d_in[6];
    const float* beta   = (const float*)d_in[7];
    const float* out_w  = (const float*)d_in[8];
    const float* out_b  = (const float*)d_in[9];
    float* out = (float*)d_out;

    char* ws = (char*)d_ws;
    const long ROWS = (long)BB * NN;               // 65536
    float*  z      = (float*) (ws + 0);            // 16 MB
    float*  rst    = (float*) (ws + 16777216);     // 16 MB
    float*  s_src  = (float*) (ws + 33554432);     // 256 KB
    float*  s_dst  = (float*) (ws + 33816576);     // 256 KB
    int*    topk   = (int*)   (ws + 34078720);     // 40 KB
    float*  es_src = (float*) (ws + 34119680);     // 2 KB
    float*  es_dst = (float*) (ws + 34121728);     // 2 KB
    double* bsum   = (double*)(ws + 34123776);     // 64 KB
    double* bsum2  = (double*)(ws + 34189312);     // 64 KB
    float*  scaleA = (float*) (ws + 34254848);     // 256 B
    float*  biasA  = (float*) (ws + 34255104);     // 256 B

    k1_topk<<<NN, 64, 0, stream>>>(emb, attn_w, topk, es_src, es_dst);
    k2_gemm<<<(int)(ROWS / 64), 256, 0, stream>>>(data, fc_w, fc_b, attn_w, es_src, es_dst,
                                                  z, s_src, s_dst);
    k3_attn<<<BB * 4, 256, 0, stream>>>(z, s_src, s_dst, topk, emb, attn_b, rst, bsum, bsum2);
    k4_bn<<<1, 64, 0, stream>>>(bsum, bsum2, gamma, beta, scaleA, biasA);
    k5_out<<<(int)(ROWS / 4), 256, 0, stream>>>(rst, scaleA, biasA, out_w, out_b, out);
}